// Round 1
// baseline (409.566 us; speedup 1.0000x reference)
//
#include <hip/hip_runtime.h>

// MHA forward on MI355X (gfx950), bf16 MFMA pipeline.
// B=4, S=2048, H=16, Dk=Dv=64, Dmodel=1024.
//
// Pipeline:
//   1. wtrans x4: W[1024][1024] fp32 -> WT[n][k] bf16 (Wq scaled by 1/8)
//   2. gemm128<AF32=1,MODE=0> x3: qh/kh/vh = X @ W + b, scattered to [B,H,S,64] bf16
//   3. attn64: flash attention per (b,h), 64 q-rows/block -> attnout [B,S,1024] bf16
//   4. gemm128<AF32=0,MODE=1>: out = attnout @ Wo + bo, fp32
//
// Workspace layout (72 MB total):
//   [0,8MB)    WqT/WkT/WvT/WoT bf16 (2MB each)
//   [8,24MB)   qh, [24,40MB) kh, [40,56MB) vh   ([B,H,S,64] bf16)
//   [56,72MB)  attnout ([B,S,1024] bf16)

typedef __attribute__((ext_vector_type(8))) short bf16x8;
typedef __attribute__((ext_vector_type(4))) float f32x4;

__device__ __forceinline__ unsigned short f2bf(float x) {
  unsigned u = __builtin_bit_cast(unsigned, x);
  u += 0x7fffu + ((u >> 16) & 1u);   // RNE; inputs are finite
  return (unsigned short)(u >> 16);
}

// ---------------------------------------------------------------------------
// Weight transpose+convert: W[k][n] fp32 -> WT[n][k] bf16, scaled.
// ---------------------------------------------------------------------------
__global__ void wtrans(const float* __restrict__ W, unsigned short* __restrict__ WT,
                       float scale) {
  __shared__ float t[32][33];
  int x = threadIdx.x, y = threadIdx.y;
  int k0 = blockIdx.x * 32, n0 = blockIdx.y * 32;
#pragma unroll
  for (int i = 0; i < 4; i++)
    t[y + i * 8][x] = W[(k0 + y + i * 8) * 1024 + n0 + x];
  __syncthreads();
#pragma unroll
  for (int i = 0; i < 4; i++)
    WT[(n0 + y + i * 8) * 1024 + k0 + x] = f2bf(t[x][y + i * 8] * scale);
}

// ---------------------------------------------------------------------------
// 128x128x(K=1024) GEMM, BK=32, 4 waves (each 64x64 = 4x4 frags of 16x16x32).
// A: [8192][1024] row-major (fp32 if AF32 else bf16). BT: [1024 n][1024 k] bf16.
// MODE 0: C -> bf16 scatter to [B,H,S,64] (+bias*bscale).
// MODE 1: C -> fp32 [8192][1024] (+bias).
// LDS tiles XOR-swizzled: byte ^= (row&7)<<4  (T2; conflict-free b128 reads).
// ---------------------------------------------------------------------------
template <bool AF32, int MODE>
__global__ __launch_bounds__(256, 2) void gemm128(
    const void* __restrict__ Ap, const unsigned short* __restrict__ BT,
    const float* __restrict__ bias, float bscale, void* __restrict__ Cp) {
  __shared__ __align__(16) char As[8192];
  __shared__ __align__(16) char Bs[8192];
  const int K = 1024;
  int tid = threadIdx.x;
  int lane = tid & 63;
  int w = tid >> 6;
  int wr = w >> 1, wc = w & 1;
  int m0 = blockIdx.y * 128, n0 = blockIdx.x * 128;
  int r = tid >> 1;            // staging row 0..127
  int kb = (tid & 1) << 4;     // staging k-offset (elements): 0 or 16

  f32x4 acc[4][4];
#pragma unroll
  for (int i = 0; i < 4; i++)
#pragma unroll
    for (int j = 0; j < 4; j++) acc[i][j] = (f32x4){0.f, 0.f, 0.f, 0.f};

  const float* Af = (const float*)Ap;
  const unsigned short* Ab = (const unsigned short*)Ap;

  f32x4 afr[4];
  bf16x8 afb[2];
  bf16x8 bfr[2];

  // initial loads (k0 = 0)
  if (AF32) {
    const f32x4* p = (const f32x4*)(Af + (size_t)(m0 + r) * K + kb);
#pragma unroll
    for (int i = 0; i < 4; i++) afr[i] = p[i];
  } else {
    const bf16x8* p = (const bf16x8*)(Ab + (size_t)(m0 + r) * K + kb);
    afb[0] = p[0]; afb[1] = p[1];
  }
  {
    const bf16x8* p = (const bf16x8*)(BT + (size_t)(n0 + r) * K + kb);
    bfr[0] = p[0]; bfr[1] = p[1];
  }

  int swz = (r & 7) << 4;
  int wbyte = r * 64 + kb * 2;
  int cc = lane & 15, g = lane >> 4;

  for (int k0 = 0; k0 < K; k0 += 32) {
    __syncthreads();
    // ---- write staged tile to LDS
    if (AF32) {
      bf16x8 s0, s1;
#pragma unroll
      for (int i = 0; i < 8; i++) {
        s0[i] = (short)f2bf(afr[i >> 2][i & 3]);
        s1[i] = (short)f2bf(afr[2 + (i >> 2)][i & 3]);
      }
      *(bf16x8*)(As + (wbyte ^ swz)) = s0;
      *(bf16x8*)(As + ((wbyte + 16) ^ swz)) = s1;
    } else {
      *(bf16x8*)(As + (wbyte ^ swz)) = afb[0];
      *(bf16x8*)(As + ((wbyte + 16) ^ swz)) = afb[1];
    }
    *(bf16x8*)(Bs + (wbyte ^ swz)) = bfr[0];
    *(bf16x8*)(Bs + ((wbyte + 16) ^ swz)) = bfr[1];
    // ---- issue next tile's global loads (land during compute)
    if (k0 + 32 < K) {
      if (AF32) {
        const f32x4* p = (const f32x4*)(Af + (size_t)(m0 + r) * K + k0 + 32 + kb);
#pragma unroll
        for (int i = 0; i < 4; i++) afr[i] = p[i];
      } else {
        const bf16x8* p = (const bf16x8*)(Ab + (size_t)(m0 + r) * K + k0 + 32 + kb);
        afb[0] = p[0]; afb[1] = p[1];
      }
      const bf16x8* p = (const bf16x8*)(BT + (size_t)(n0 + r) * K + k0 + 32 + kb);
      bfr[0] = p[0]; bfr[1] = p[1];
    }
    __syncthreads();
    // ---- compute
    bf16x8 a[4], b[4];
#pragma unroll
    for (int mi = 0; mi < 4; mi++) {
      int row = wr * 64 + mi * 16 + cc;
      int byte = (row * 64 + g * 16) ^ ((row & 7) << 4);
      a[mi] = *(const bf16x8*)(As + byte);
    }
#pragma unroll
    for (int ni = 0; ni < 4; ni++) {
      int row = wc * 64 + ni * 16 + cc;
      int byte = (row * 64 + g * 16) ^ ((row & 7) << 4);
      b[ni] = *(const bf16x8*)(Bs + byte);
    }
#pragma unroll
    for (int mi = 0; mi < 4; mi++)
#pragma unroll
      for (int ni = 0; ni < 4; ni++)
        acc[mi][ni] =
            __builtin_amdgcn_mfma_f32_16x16x32_bf16(a[mi], b[ni], acc[mi][ni], 0, 0, 0);
  }

  // ---- epilogue. C/D map: col = lane&15, row = (lane>>4)*4 + j.
#pragma unroll
  for (int ni = 0; ni < 4; ni++) {
    int n = n0 + wc * 64 + ni * 16 + cc;
    float bv = bias[n] * bscale;
#pragma unroll
    for (int mi = 0; mi < 4; mi++) {
#pragma unroll
      for (int j = 0; j < 4; j++) {
        float val = acc[mi][ni][j] + bv;
        int m = m0 + wr * 64 + mi * 16 + g * 4 + j;
        if (MODE == 0) {
          int bb = m >> 11, s = m & 2047;
          int hh = n >> 6, d = n & 63;
          ((unsigned short*)Cp)[(((bb * 16 + hh) * 2048 + s) << 6) + d] = f2bf(val);
        } else {
          ((float*)Cp)[(size_t)m * 1024 + n] = val;
        }
      }
    }
  }
}

// ---------------------------------------------------------------------------
// Flash attention. Grid: (S/64, B*H). Block: 256 thr = 4 waves x 16 q-rows.
// KV-tile = 128. qh/kh/vh are [B,H,S,64] bf16; scale 1/8 pre-folded into Wq.
// Out: attnout [B,S,H*64] bf16.
// ---------------------------------------------------------------------------
__global__ __launch_bounds__(256, 2) void attn64(
    const unsigned short* __restrict__ Qh, const unsigned short* __restrict__ Kh,
    const unsigned short* __restrict__ Vh, unsigned short* __restrict__ O) {
  __shared__ __align__(16) char Ks[16384];      // [128 k][64 d] swizzled
  __shared__ __align__(16) char Vt[16384];      // [64 d][128 k] swizzled (transposed)
  __shared__ __align__(16) char Ps[4][4096];    // per-wave P [16 q][128 k] swizzled
  int tid = threadIdx.x, lane = tid & 63, w = tid >> 6;
  int bh = blockIdx.y;
  int b = bh >> 4, h = bh & 15;
  const unsigned short* Q = Qh + (size_t)bh * (2048 * 64);
  const unsigned short* Kb = Kh + (size_t)bh * (2048 * 64);
  const unsigned short* Vb = Vh + (size_t)bh * (2048 * 64);
  int q0 = blockIdx.x * 64 + w * 16;
  int cc = lane & 15, g = lane >> 4;

  // Q fragments held in registers: a[g2][j] = Q[q0 + (lane&15)][g2*32 + (lane>>4)*8 + j]
  bf16x8 aq[2];
#pragma unroll
  for (int g2 = 0; g2 < 2; g2++)
    aq[g2] = *(const bf16x8*)(Q + (size_t)(q0 + cc) * 64 + g2 * 32 + g * 8);

  f32x4 oacc[4];
#pragma unroll
  for (int df = 0; df < 4; df++) oacc[df] = (f32x4){0.f, 0.f, 0.f, 0.f};
  float mrun[4], lrun[4];
#pragma unroll
  for (int j = 0; j < 4; j++) { mrun[j] = -1e30f; lrun[j] = 0.f; }

  int r = tid >> 1, seg = tid & 1;

  for (int kt = 0; kt < 2048; kt += 128) {
    // global loads for this KV tile (64B per thread each)
    bf16x8 kv[4], vv[4];
    {
      const bf16x8* pK = (const bf16x8*)(Kb + (size_t)(kt + r) * 64 + seg * 32);
      const bf16x8* pV = (const bf16x8*)(Vb + (size_t)(kt + r) * 64 + seg * 32);
#pragma unroll
      for (int i = 0; i < 4; i++) { kv[i] = pK[i]; vv[i] = pV[i]; }
    }
    __syncthreads();
    int swz = (r & 7) << 4;
    int kbyte = r * 128 + seg * 64;
#pragma unroll
    for (int i = 0; i < 4; i++)
      *(bf16x8*)(Ks + ((kbyte + i * 16) ^ swz)) = kv[i];
#pragma unroll
    for (int e = 0; e < 32; e++) {   // V transposed, scalar u16 writes
      int dv = seg * 32 + e;
      int byte = (dv * 256 + r * 2) ^ ((dv & 7) << 4);
      *(short*)(Vt + byte) = vv[e >> 3][e & 7];
    }
    __syncthreads();

    // ---- QK^T: sc[nf] holds scores[q-rows][nf*16..+16]
    f32x4 sc[8];
#pragma unroll
    for (int nf = 0; nf < 8; nf++) sc[nf] = (f32x4){0.f, 0.f, 0.f, 0.f};
#pragma unroll
    for (int nf = 0; nf < 8; nf++) {
#pragma unroll
      for (int g2 = 0; g2 < 2; g2++) {
        int rk = nf * 16 + cc;
        int byte = (rk * 128 + g2 * 64 + g * 16) ^ ((rk & 7) << 4);
        bf16x8 bk = *(const bf16x8*)(Ks + byte);
        sc[nf] = __builtin_amdgcn_mfma_f32_16x16x32_bf16(aq[g2], bk, sc[nf], 0, 0, 0);
      }
    }

    // ---- online softmax (row j lives in lanes sharing lane>>4; reduce over lane&15)
    float scl[4];
#pragma unroll
    for (int j = 0; j < 4; j++) {
      float mx = sc[0][j];
#pragma unroll
      for (int nf = 1; nf < 8; nf++) mx = fmaxf(mx, sc[nf][j]);
      mx = fmaxf(mx, __shfl_xor(mx, 1));
      mx = fmaxf(mx, __shfl_xor(mx, 2));
      mx = fmaxf(mx, __shfl_xor(mx, 4));
      mx = fmaxf(mx, __shfl_xor(mx, 8));
      float mn = fmaxf(mrun[j], mx);
      scl[j] = __expf(mrun[j] - mn);
      mrun[j] = mn;
    }
#pragma unroll
    for (int df = 0; df < 4; df++)
#pragma unroll
      for (int j = 0; j < 4; j++) oacc[df][j] *= scl[j];
    float ps[4] = {0.f, 0.f, 0.f, 0.f};
#pragma unroll
    for (int nf = 0; nf < 8; nf++)
#pragma unroll
      for (int j = 0; j < 4; j++) {
        float p = __expf(sc[nf][j] - mrun[j]);
        sc[nf][j] = p;
        ps[j] += p;
      }
#pragma unroll
    for (int j = 0; j < 4; j++) {
      float s = ps[j];
      s += __shfl_xor(s, 1);
      s += __shfl_xor(s, 2);
      s += __shfl_xor(s, 4);
      s += __shfl_xor(s, 8);
      lrun[j] = lrun[j] * scl[j] + s;
    }

    // ---- P -> per-wave LDS (bf16), then PV
#pragma unroll
    for (int nf = 0; nf < 8; nf++)
#pragma unroll
      for (int j = 0; j < 4; j++) {
        int prow = g * 4 + j;
        int byte = (prow * 256 + (nf * 16 + cc) * 2) ^ ((prow & 7) << 4);
        *(short*)(Ps[w] + byte) = (short)f2bf(sc[nf][j]);
      }
    bf16x8 pa[4];
#pragma unroll
    for (int kk = 0; kk < 4; kk++) {
      int byte = (cc * 256 + kk * 64 + g * 16) ^ ((cc & 7) << 4);
      pa[kk] = *(const bf16x8*)(Ps[w] + byte);
    }
#pragma unroll
    for (int df = 0; df < 4; df++) {
#pragma unroll
      for (int kk = 0; kk < 4; kk++) {
        int rv = df * 16 + cc;
        int byte = (rv * 256 + kk * 64 + g * 16) ^ ((rv & 7) << 4);
        bf16x8 bv = *(const bf16x8*)(Vt + byte);
        oacc[df] = __builtin_amdgcn_mfma_f32_16x16x32_bf16(pa[kk], bv, oacc[df], 0, 0, 0);
      }
    }
  }

  // ---- epilogue: normalize and store attnout[b][s][h*64+d]
#pragma unroll
  for (int j = 0; j < 4; j++) {
    float inv = 1.0f / lrun[j];
    int srow = q0 + g * 4 + j;
#pragma unroll
    for (int df = 0; df < 4; df++) {
      int d = df * 16 + cc;
      O[((size_t)b * 2048 + srow) * 1024 + h * 64 + d] = f2bf(oacc[df][j] * inv);
    }
  }
}

// ---------------------------------------------------------------------------
extern "C" void kernel_launch(void* const* d_in, const int* in_sizes, int n_in,
                              void* d_out, int out_size, void* d_ws, size_t ws_size,
                              hipStream_t stream) {
  const float* q  = (const float*)d_in[0];
  const float* k  = (const float*)d_in[1];
  const float* v  = (const float*)d_in[2];
  const float* Wq = (const float*)d_in[3];
  const float* bq = (const float*)d_in[4];
  const float* Wk = (const float*)d_in[5];
  const float* bk = (const float*)d_in[6];
  const float* Wv = (const float*)d_in[7];
  const float* bv = (const float*)d_in[8];
  const float* Wo = (const float*)d_in[9];
  const float* bo = (const float*)d_in[10];

  char* ws = (char*)d_ws;
  const size_t MB = 1024 * 1024;
  unsigned short* WqT = (unsigned short*)(ws + 0 * MB);
  unsigned short* WkT = (unsigned short*)(ws + 2 * MB);
  unsigned short* WvT = (unsigned short*)(ws + 4 * MB);
  unsigned short* WoT = (unsigned short*)(ws + 6 * MB);
  unsigned short* qh  = (unsigned short*)(ws + 8 * MB);
  unsigned short* kh  = (unsigned short*)(ws + 24 * MB);
  unsigned short* vh  = (unsigned short*)(ws + 40 * MB);
  unsigned short* ao  = (unsigned short*)(ws + 56 * MB);

  dim3 tb(32, 8);
  // scale 1/sqrt(64) = 1/8 folded into Wq (and bq via bscale)
  wtrans<<<dim3(32, 32), tb, 0, stream>>>(Wq, WqT, 0.125f);
  wtrans<<<dim3(32, 32), tb, 0, stream>>>(Wk, WkT, 1.0f);
  wtrans<<<dim3(32, 32), tb, 0, stream>>>(Wv, WvT, 1.0f);
  wtrans<<<dim3(32, 32), tb, 0, stream>>>(Wo, WoT, 1.0f);

  gemm128<true, 0><<<dim3(8, 64), 256, 0, stream>>>(q, WqT, bq, 0.125f, qh);
  gemm128<true, 0><<<dim3(8, 64), 256, 0, stream>>>(k, WkT, bk, 1.0f, kh);
  gemm128<true, 0><<<dim3(8, 64), 256, 0, stream>>>(v, WvT, bv, 1.0f, vh);

  attn64<<<dim3(32, 64), 256, 0, stream>>>(qh, kh, vh, ao);

  gemm128<false, 1><<<dim3(8, 64), 256, 0, stream>>>(ao, WoT, bo, 1.0f, d_out);
}

// Round 2
// 362.924 us; speedup vs baseline: 1.1285x; 1.1285x over previous
//
#include <hip/hip_runtime.h>

// MHA forward on MI355X (gfx950), bf16 MFMA pipeline.
// B=4, S=2048, H=16, Dk=Dv=64, Dmodel=1024.
//
// Pipeline:
//   1. wtrans x4: W[1024][1024] fp32 -> WT[n][k] bf16 (Wq scaled by 1/8)
//   2. gemm128<AF32,MODE>: qh/kh = X@W+b -> [B,H,S,64] bf16 (MODE 0)
//      vh -> TRANSPOSED [B,H,64,S] bf16 (MODE 2) so attn needs no V transpose
//   3. attn64: flash attention, prefetched KV tiles, XCD-swizzled grid
//   4. gemm128<false,1>: out = attnout @ Wo + bo, fp32
//
// Workspace layout (72 MB total):
//   [0,8MB)    WqT/WkT/WvT/WoT bf16 (2MB each)
//   [8,24MB)   qh [B,H,S,64], [24,40MB) kh [B,H,S,64], [40,56MB) vt [B,H,64,S]
//   [56,72MB)  attnout ([B,S,1024] bf16)

typedef __attribute__((ext_vector_type(8))) short bf16x8;
typedef __attribute__((ext_vector_type(4))) float f32x4;
typedef __attribute__((ext_vector_type(4))) unsigned short u16x4;

__device__ __forceinline__ unsigned short f2bf(float x) {
  unsigned u = __builtin_bit_cast(unsigned, x);
  u += 0x7fffu + ((u >> 16) & 1u);   // RNE; inputs are finite
  return (unsigned short)(u >> 16);
}

// ---------------------------------------------------------------------------
// Weight transpose+convert: W[k][n] fp32 -> WT[n][k] bf16, scaled.
// ---------------------------------------------------------------------------
__global__ void wtrans(const float* __restrict__ W, unsigned short* __restrict__ WT,
                       float scale) {
  __shared__ float t[32][33];
  int x = threadIdx.x, y = threadIdx.y;
  int k0 = blockIdx.x * 32, n0 = blockIdx.y * 32;
#pragma unroll
  for (int i = 0; i < 4; i++)
    t[y + i * 8][x] = W[(k0 + y + i * 8) * 1024 + n0 + x];
  __syncthreads();
#pragma unroll
  for (int i = 0; i < 4; i++)
    WT[(n0 + y + i * 8) * 1024 + k0 + x] = f2bf(t[x][y + i * 8] * scale);
}

// ---------------------------------------------------------------------------
// 128x128x(K=1024) GEMM, BK=32, 4 waves (each 64x64 = 4x4 frags of 16x16x32).
// A: [8192][1024] row-major (fp32 if AF32 else bf16). BT: [1024 n][1024 k] bf16.
// MODE 0: C -> bf16 scatter to [B,H,S,64] (+bias*bscale).
// MODE 1: C -> fp32 [8192][1024] (+bias).
// MODE 2: C -> bf16 TRANSPOSED scatter to [B,H,64,S] (packed 8B stores).
// LDS tiles XOR-swizzled: byte ^= (row&7)<<4  (T2; conflict-free b128 reads).
// ---------------------------------------------------------------------------
template <bool AF32, int MODE>
__global__ __launch_bounds__(256, 2) void gemm128(
    const void* __restrict__ Ap, const unsigned short* __restrict__ BT,
    const float* __restrict__ bias, float bscale, void* __restrict__ Cp) {
  __shared__ __align__(16) char As[8192];
  __shared__ __align__(16) char Bs[8192];
  const int K = 1024;
  int tid = threadIdx.x;
  int lane = tid & 63;
  int w = tid >> 6;
  int wr = w >> 1, wc = w & 1;
  int m0 = blockIdx.y * 128, n0 = blockIdx.x * 128;
  int r = tid >> 1;            // staging row 0..127
  int kb = (tid & 1) << 4;     // staging k-offset (elements): 0 or 16

  f32x4 acc[4][4];
#pragma unroll
  for (int i = 0; i < 4; i++)
#pragma unroll
    for (int j = 0; j < 4; j++) acc[i][j] = (f32x4){0.f, 0.f, 0.f, 0.f};

  const float* Af = (const float*)Ap;
  const unsigned short* Ab = (const unsigned short*)Ap;

  f32x4 afr[4];
  bf16x8 afb[2];
  bf16x8 bfr[2];

  // initial loads (k0 = 0)
  if (AF32) {
    const f32x4* p = (const f32x4*)(Af + (size_t)(m0 + r) * K + kb);
#pragma unroll
    for (int i = 0; i < 4; i++) afr[i] = p[i];
  } else {
    const bf16x8* p = (const bf16x8*)(Ab + (size_t)(m0 + r) * K + kb);
    afb[0] = p[0]; afb[1] = p[1];
  }
  {
    const bf16x8* p = (const bf16x8*)(BT + (size_t)(n0 + r) * K + kb);
    bfr[0] = p[0]; bfr[1] = p[1];
  }

  int swz = (r & 7) << 4;
  int wbyte = r * 64 + kb * 2;
  int cc = lane & 15, g = lane >> 4;

  for (int k0 = 0; k0 < K; k0 += 32) {
    __syncthreads();
    // ---- write staged tile to LDS
    if (AF32) {
      bf16x8 s0, s1;
#pragma unroll
      for (int i = 0; i < 8; i++) {
        s0[i] = (short)f2bf(afr[i >> 2][i & 3]);
        s1[i] = (short)f2bf(afr[2 + (i >> 2)][i & 3]);
      }
      *(bf16x8*)(As + (wbyte ^ swz)) = s0;
      *(bf16x8*)(As + ((wbyte + 16) ^ swz)) = s1;
    } else {
      *(bf16x8*)(As + (wbyte ^ swz)) = afb[0];
      *(bf16x8*)(As + ((wbyte + 16) ^ swz)) = afb[1];
    }
    *(bf16x8*)(Bs + (wbyte ^ swz)) = bfr[0];
    *(bf16x8*)(Bs + ((wbyte + 16) ^ swz)) = bfr[1];
    // ---- issue next tile's global loads (land during compute)
    if (k0 + 32 < K) {
      if (AF32) {
        const f32x4* p = (const f32x4*)(Af + (size_t)(m0 + r) * K + k0 + 32 + kb);
#pragma unroll
        for (int i = 0; i < 4; i++) afr[i] = p[i];
      } else {
        const bf16x8* p = (const bf16x8*)(Ab + (size_t)(m0 + r) * K + k0 + 32 + kb);
        afb[0] = p[0]; afb[1] = p[1];
      }
      const bf16x8* p = (const bf16x8*)(BT + (size_t)(n0 + r) * K + k0 + 32 + kb);
      bfr[0] = p[0]; bfr[1] = p[1];
    }
    __syncthreads();
    // ---- compute
    bf16x8 a[4], b[4];
#pragma unroll
    for (int mi = 0; mi < 4; mi++) {
      int row = wr * 64 + mi * 16 + cc;
      int byte = (row * 64 + g * 16) ^ ((row & 7) << 4);
      a[mi] = *(const bf16x8*)(As + byte);
    }
#pragma unroll
    for (int ni = 0; ni < 4; ni++) {
      int row = wc * 64 + ni * 16 + cc;
      int byte = (row * 64 + g * 16) ^ ((row & 7) << 4);
      b[ni] = *(const bf16x8*)(Bs + byte);
    }
#pragma unroll
    for (int mi = 0; mi < 4; mi++)
#pragma unroll
      for (int ni = 0; ni < 4; ni++)
        acc[mi][ni] =
            __builtin_amdgcn_mfma_f32_16x16x32_bf16(a[mi], b[ni], acc[mi][ni], 0, 0, 0);
  }

  // ---- epilogue. C/D map: col = lane&15, row = (lane>>4)*4 + j.
#pragma unroll
  for (int ni = 0; ni < 4; ni++) {
    int n = n0 + wc * 64 + ni * 16 + cc;
    float bv = bias[n] * bscale;
#pragma unroll
    for (int mi = 0; mi < 4; mi++) {
      int mbase = m0 + wr * 64 + mi * 16 + g * 4;
      if (MODE == 2) {
        // transposed: pack 4 consecutive s at fixed d -> one 8B store
        u16x4 pk;
#pragma unroll
        for (int j = 0; j < 4; j++) pk[j] = f2bf(acc[mi][ni][j] + bv);
        int bb = mbase >> 11, s = mbase & 2047;
        int hh = n >> 6, d = n & 63;
        *(u16x4*)&((unsigned short*)Cp)[(((size_t)(bb * 16 + hh) * 64 + d) << 11) + s] = pk;
      } else {
#pragma unroll
        for (int j = 0; j < 4; j++) {
          float val = acc[mi][ni][j] + bv;
          int m = mbase + j;
          if (MODE == 0) {
            int bb = m >> 11, s = m & 2047;
            int hh = n >> 6, d = n & 63;
            ((unsigned short*)Cp)[(((bb * 16 + hh) * 2048 + s) << 6) + d] = f2bf(val);
          } else {
            ((float*)Cp)[(size_t)m * 1024 + n] = val;
          }
        }
      }
    }
  }
}

// ---------------------------------------------------------------------------
// Flash attention. Grid: 2048 blocks (XCD-swizzled). Block: 4 waves x 16 q-rows.
// KV-tile = 128, single-buffered LDS with register prefetch of tile t+1.
// qh/kh: [B,H,S,64] bf16. vt: [B,H,64,S] bf16 (pre-transposed).
// Out: attnout [B,S,H*64] bf16. Scale 1/8 pre-folded into Wq.
// ---------------------------------------------------------------------------
__global__ __launch_bounds__(256, 2) void attn64(
    const unsigned short* __restrict__ Qh, const unsigned short* __restrict__ Kh,
    const unsigned short* __restrict__ Vt, unsigned short* __restrict__ O) {
  __shared__ __align__(16) char Ks[16384];      // [128 k][64 d] swizzled
  __shared__ __align__(16) char Vs[16384];      // [64 d][128 k] swizzled
  __shared__ __align__(16) char Ps[4][4096];    // per-wave P [16 q][128 k] swizzled
  int tid = threadIdx.x, lane = tid & 63, w = tid >> 6;
  // XCD swizzle: each XCD gets 8 consecutive bh values (K/V L2-resident)
  int bid = blockIdx.x;
  int sid = (bid & 7) * 256 + (bid >> 3);
  int bh = sid >> 5, qb = sid & 31;
  int b = bh >> 4, h = bh & 15;
  const unsigned short* Q  = Qh + (size_t)bh * (2048 * 64);
  const unsigned short* Kb = Kh + (size_t)bh * (2048 * 64);
  const unsigned short* Vb = Vt + (size_t)bh * (64 * 2048);
  int q0 = qb * 64 + w * 16;
  int cc = lane & 15, g = lane >> 4;

  // Q fragments in registers: aq[g2] = Q[q0+cc][g2*32 + g*8 .. +8]
  bf16x8 aq[2];
#pragma unroll
  for (int g2 = 0; g2 < 2; g2++)
    aq[g2] = *(const bf16x8*)(Q + (size_t)(q0 + cc) * 64 + g2 * 32 + g * 8);

  f32x4 oacc[4];
#pragma unroll
  for (int df = 0; df < 4; df++) oacc[df] = (f32x4){0.f, 0.f, 0.f, 0.f};
  float mrun[4], lrun[4];
#pragma unroll
  for (int j = 0; j < 4; j++) { mrun[j] = -1e30f; lrun[j] = 0.f; }

  // staging indices
  int kr = tid >> 1, kseg = tid & 1;      // K: row 0..127, 32-elem half
  int vr = tid >> 2, vq = tid & 3;        // V^T: row 0..63, 32-elem quarter
  int kswz = (kr & 7) << 4;
  int vswz = (vr & 7) << 4;
  int kbyte = kr * 128 + kseg * 64;
  int vbyte = vr * 256 + vq * 64;

  // prefetch tile 0 into registers
  bf16x8 kv[4], vv[4];
  {
    const bf16x8* pK = (const bf16x8*)(Kb + (size_t)kr * 64 + kseg * 32);
    const bf16x8* pV = (const bf16x8*)(Vb + (size_t)vr * 2048 + vq * 32);
#pragma unroll
    for (int i = 0; i < 4; i++) { kv[i] = pK[i]; vv[i] = pV[i]; }
  }

  for (int kt = 0; kt < 2048; kt += 128) {
    __syncthreads();   // previous tile's compute done; LDS free
#pragma unroll
    for (int i = 0; i < 4; i++) {
      *(bf16x8*)(Ks + ((kbyte + i * 16) ^ kswz)) = kv[i];
      *(bf16x8*)(Vs + ((vbyte + i * 16) ^ vswz)) = vv[i];
    }
    __syncthreads();   // LDS ready
    // ---- issue next tile's global loads; land during compute below
    if (kt + 128 < 2048) {
      const bf16x8* pK = (const bf16x8*)(Kb + (size_t)(kt + 128 + kr) * 64 + kseg * 32);
      const bf16x8* pV = (const bf16x8*)(Vb + (size_t)vr * 2048 + kt + 128 + vq * 32);
#pragma unroll
      for (int i = 0; i < 4; i++) { kv[i] = pK[i]; vv[i] = pV[i]; }
    }

    // ---- QK^T: sc[nf] holds scores[q-rows][nf*16..+16]
    f32x4 sc[8];
#pragma unroll
    for (int nf = 0; nf < 8; nf++) sc[nf] = (f32x4){0.f, 0.f, 0.f, 0.f};
    __builtin_amdgcn_s_setprio(1);
#pragma unroll
    for (int nf = 0; nf < 8; nf++) {
#pragma unroll
      for (int g2 = 0; g2 < 2; g2++) {
        int rk = nf * 16 + cc;
        int byte = (rk * 128 + g2 * 64 + g * 16) ^ ((rk & 7) << 4);
        bf16x8 bk = *(const bf16x8*)(Ks + byte);
        sc[nf] = __builtin_amdgcn_mfma_f32_16x16x32_bf16(aq[g2], bk, sc[nf], 0, 0, 0);
      }
    }
    __builtin_amdgcn_s_setprio(0);

    // ---- online softmax (row j lives in lanes sharing lane>>4; reduce over lane&15)
    float scl[4];
#pragma unroll
    for (int j = 0; j < 4; j++) {
      float mx = fmaxf(fmaxf(fmaxf(sc[0][j], sc[1][j]), fmaxf(sc[2][j], sc[3][j])),
                       fmaxf(fmaxf(sc[4][j], sc[5][j]), fmaxf(sc[6][j], sc[7][j])));
      mx = fmaxf(mx, __shfl_xor(mx, 1));
      mx = fmaxf(mx, __shfl_xor(mx, 2));
      mx = fmaxf(mx, __shfl_xor(mx, 4));
      mx = fmaxf(mx, __shfl_xor(mx, 8));
      float mn = fmaxf(mrun[j], mx);
      scl[j] = __expf(mrun[j] - mn);
      mrun[j] = mn;
    }
#pragma unroll
    for (int df = 0; df < 4; df++)
#pragma unroll
      for (int j = 0; j < 4; j++) oacc[df][j] *= scl[j];
    float ps[4] = {0.f, 0.f, 0.f, 0.f};
#pragma unroll
    for (int nf = 0; nf < 8; nf++)
#pragma unroll
      for (int j = 0; j < 4; j++) {
        float p = __expf(sc[nf][j] - mrun[j]);
        sc[nf][j] = p;
        ps[j] += p;
      }
#pragma unroll
    for (int j = 0; j < 4; j++) {
      float s = ps[j];
      s += __shfl_xor(s, 1);
      s += __shfl_xor(s, 2);
      s += __shfl_xor(s, 4);
      s += __shfl_xor(s, 8);
      lrun[j] = lrun[j] * scl[j] + s;
    }

    // ---- P -> per-wave LDS (bf16), then PV
#pragma unroll
    for (int nf = 0; nf < 8; nf++)
#pragma unroll
      for (int j = 0; j < 4; j++) {
        int prow = g * 4 + j;
        int byte = (prow * 256 + (nf * 16 + cc) * 2) ^ ((prow & 7) << 4);
        *(short*)(Ps[w] + byte) = (short)f2bf(sc[nf][j]);
      }
    bf16x8 pa[4];
#pragma unroll
    for (int kk = 0; kk < 4; kk++) {
      int byte = (cc * 256 + kk * 64 + g * 16) ^ ((cc & 7) << 4);
      pa[kk] = *(const bf16x8*)(Ps[w] + byte);
    }
    __builtin_amdgcn_s_setprio(1);
#pragma unroll
    for (int df = 0; df < 4; df++) {
#pragma unroll
      for (int kk = 0; kk < 4; kk++) {
        int rv = df * 16 + cc;
        int byte = (rv * 256 + kk * 64 + g * 16) ^ ((rv & 7) << 4);
        bf16x8 bv = *(const bf16x8*)(Vs + byte);
        oacc[df] = __builtin_amdgcn_mfma_f32_16x16x32_bf16(pa[kk], bv, oacc[df], 0, 0, 0);
      }
    }
    __builtin_amdgcn_s_setprio(0);
  }

  // ---- epilogue: normalize and store attnout[b][s][h*64+d]
#pragma unroll
  for (int j = 0; j < 4; j++) {
    float inv = 1.0f / lrun[j];
    int srow = q0 + g * 4 + j;
#pragma unroll
    for (int df = 0; df < 4; df++) {
      int d = df * 16 + cc;
      O[((size_t)b * 2048 + srow) * 1024 + h * 64 + d] = f2bf(oacc[df][j] * inv);
    }
  }
}

// ---------------------------------------------------------------------------
extern "C" void kernel_launch(void* const* d_in, const int* in_sizes, int n_in,
                              void* d_out, int out_size, void* d_ws, size_t ws_size,
                              hipStream_t stream) {
  const float* q  = (const float*)d_in[0];
  const float* k  = (const float*)d_in[1];
  const float* v  = (const float*)d_in[2];
  const float* Wq = (const float*)d_in[3];
  const float* bq = (const float*)d_in[4];
  const float* Wk = (const float*)d_in[5];
  const float* bk = (const float*)d_in[6];
  const float* Wv = (const float*)d_in[7];
  const float* bv = (const float*)d_in[8];
  const float* Wo = (const float*)d_in[9];
  const float* bo = (const float*)d_in[10];

  char* ws = (char*)d_ws;
  const size_t MB = 1024 * 1024;
  unsigned short* WqT = (unsigned short*)(ws + 0 * MB);
  unsigned short* WkT = (unsigned short*)(ws + 2 * MB);
  unsigned short* WvT = (unsigned short*)(ws + 4 * MB);
  unsigned short* WoT = (unsigned short*)(ws + 6 * MB);
  unsigned short* qh  = (unsigned short*)(ws + 8 * MB);
  unsigned short* kh  = (unsigned short*)(ws + 24 * MB);
  unsigned short* vt  = (unsigned short*)(ws + 40 * MB);
  unsigned short* ao  = (unsigned short*)(ws + 56 * MB);

  dim3 tb(32, 8);
  // scale 1/sqrt(64) = 1/8 folded into Wq (and bq via bscale)
  wtrans<<<dim3(32, 32), tb, 0, stream>>>(Wq, WqT, 0.125f);
  wtrans<<<dim3(32, 32), tb, 0, stream>>>(Wk, WkT, 1.0f);
  wtrans<<<dim3(32, 32), tb, 0, stream>>>(Wv, WvT, 1.0f);
  wtrans<<<dim3(32, 32), tb, 0, stream>>>(Wo, WoT, 1.0f);

  gemm128<true, 0><<<dim3(8, 64), 256, 0, stream>>>(q, WqT, bq, 0.125f, qh);
  gemm128<true, 0><<<dim3(8, 64), 256, 0, stream>>>(k, WkT, bk, 1.0f, kh);
  gemm128<true, 2><<<dim3(8, 64), 256, 0, stream>>>(v, WvT, bv, 1.0f, vt);

  attn64<<<2048, 256, 0, stream>>>(qh, kh, vt, ao);

  gemm128<false, 1><<<dim3(8, 64), 256, 0, stream>>>(ao, WoT, bo, 1.0f, d_out);
}